// Round 4
// baseline (224.239 us; speedup 1.0000x reference)
//
#include <hip/hip_runtime.h>
#include <stdint.h>

#define BB 4
#define CC 256
#define NN 16384  // 128*128
#define NSL 32    // gram split-K slices

typedef unsigned short u16;
typedef __attribute__((ext_vector_type(8))) __bf16 bf16x8;
typedef __attribute__((ext_vector_type(4))) float f32x4;

// fp32 -> bf16 round-to-nearest-even
__device__ __forceinline__ u16 f2bf(float f) {
  union { float f; uint32_t u; } c;
  c.f = f;
  uint32_t u = c.u;
  return (u16)((u + 0x7fffu + ((u >> 16) & 1u)) >> 16);
}

// async global->LDS, 16 bytes per lane (global_load_lds_dwordx4)
__device__ __forceinline__ void g2l16(const u16* g, u16* l) {
  __builtin_amdgcn_global_load_lds((__attribute__((address_space(1))) void*)g,
                                   (__attribute__((address_space(3))) void*)l, 16, 0, 0);
}

// 512-thread block: stage 256x32 panel (row stride `stride`) into lds[256*32]
__device__ __forceinline__ void stage256x32_w8(const u16* src, int stride, u16* lds, int tid) {
  int r = tid >> 2;
  int c = (tid & 3) << 3;
  g2l16(src + (size_t)r * stride + c, lds + r * 32 + c);
  g2l16(src + (size_t)(r + 128) * stride + c, lds + (r + 128) * 32 + c);
}

// one 32-deep k-step: 16 MFMAs on a 64x64 per-wave tile (A,B may alias)
__device__ __forceinline__ void mfma_tile(const u16* As, const u16* Bs, int mb, int nb,
                                          int l16, int q8, f32x4 acc[4][4]) {
  bf16x8 af[4], bf[4];
#pragma unroll
  for (int i = 0; i < 4; i++) af[i] = *(const bf16x8*)&As[(mb + i * 16 + l16) * 32 + q8];
#pragma unroll
  for (int i = 0; i < 4; i++) bf[i] = *(const bf16x8*)&Bs[(nb + i * 16 + l16) * 32 + q8];
#pragma unroll
  for (int i = 0; i < 4; i++)
#pragma unroll
    for (int j = 0; j < 4; j++)
      acc[i][j] = __builtin_amdgcn_mfma_f32_16x16x32_bf16(af[i], bf[j], acc[i][j], 0, 0, 0);
}

// one 32-deep k-step: 32 MFMAs on a 64x128 per-wave tile
__device__ __forceinline__ void mfma_tile48(const u16* As, const u16* Bs, int mb, int nb,
                                            int l16, int q8, f32x4 acc[4][8]) {
  bf16x8 af[4], bf[8];
#pragma unroll
  for (int i = 0; i < 4; i++) af[i] = *(const bf16x8*)&As[(mb + i * 16 + l16) * 32 + q8];
#pragma unroll
  for (int j = 0; j < 8; j++) bf[j] = *(const bf16x8*)&Bs[(nb + j * 16 + l16) * 32 + q8];
#pragma unroll
  for (int i = 0; i < 4; i++)
#pragma unroll
    for (int j = 0; j < 8; j++)
      acc[i][j] = __builtin_amdgcn_mfma_f32_16x16x32_bf16(af[i], bf[j], acc[i][j], 0, 0, 0);
}

// prep: x fp32 (B,C,N) -> xb bf16 (B,C,N), xbT bf16 (B,N,C),
// s_part[b][ntile][c] = partial row sums (no atomics, no memset needed)
__global__ __launch_bounds__(256) void prep_kernel(const float* __restrict__ x,
                                                   u16* __restrict__ xb,
                                                   u16* __restrict__ xbT,
                                                   float* __restrict__ s_part) {
  __shared__ float t[64][65];
  __shared__ float rs[64][4];
  int n0 = blockIdx.x * 64, c0 = blockIdx.y * 64, bz = blockIdx.z;
  int tid = threadIdx.x;
  int rr0 = tid >> 4, q4 = (tid & 15) * 4;
  const float* xs = x + ((size_t)bz * CC + c0) * NN + n0;
  u16* xbp = xb + ((size_t)bz * CC + c0) * NN + n0;
#pragma unroll
  for (int cc = rr0; cc < 64; cc += 16) {
    float4 v = *(const float4*)&xs[(size_t)cc * NN + q4];
    t[cc][q4] = v.x; t[cc][q4 + 1] = v.y; t[cc][q4 + 2] = v.z; t[cc][q4 + 3] = v.w;
    union { u16 h[4]; uint2 u; } pk;
    pk.h[0] = f2bf(v.x); pk.h[1] = f2bf(v.y); pk.h[2] = f2bf(v.z); pk.h[3] = f2bf(v.w);
    *(uint2*)&xbp[(size_t)cc * NN + q4] = pk.u;
  }
  __syncthreads();
  {
    int r = tid >> 2, q = tid & 3;
    float p = 0.f;
#pragma unroll
    for (int i = 0; i < 16; i++) p += t[r][q * 16 + i];
    rs[r][q] = p;
  }
  u16* od = xbT + ((size_t)bz * NN + n0) * CC + c0;
#pragma unroll
  for (int nn = rr0; nn < 64; nn += 16) {
    union { u16 h[4]; uint2 u; } pk;
    pk.h[0] = f2bf(t[q4][nn]); pk.h[1] = f2bf(t[q4 + 1][nn]);
    pk.h[2] = f2bf(t[q4 + 2][nn]); pk.h[3] = f2bf(t[q4 + 3][nn]);
    *(uint2*)&od[(size_t)nn * CC + q4] = pk.u;
  }
  __syncthreads();
  if (tid < 64)
    s_part[((size_t)bz * 256 + blockIdx.x) * CC + c0 + tid] =
        rs[tid][0] + rs[tid][1] + rs[tid][2] + rs[tid][3];
}

// Gp[sl][b] = partial xb xb^T over K-slice sl (plain stores, NO atomics)
// v2: symmetric-operand panel sharing. One 256x32 panel per block serves as
// BOTH A and B (G is xb.xb^T). Block = 256(c) x 128(d), 8 waves (4x2 of
// 64x64). Staging traffic halves vs v1; LDS 64->32 KB.
__global__ __launch_bounds__(512) void gram_kernel(const u16* __restrict__ xb,
                                                   float* __restrict__ Gp) {
  __shared__ u16 As[2][256 * 32];
  int tid = threadIdx.x;
  int d0 = blockIdx.x * 128;
  int sl = blockIdx.y, bz = blockIdx.z;
  const u16* A = xb + (size_t)bz * CC * NN + sl * 512;
  f32x4 acc[4][4] = {};
  int wave = tid >> 6, lane = tid & 63;
  int mb = (wave & 3) * 64, nb = d0 + (wave >> 2) * 64;
  int quad = lane >> 4, l16 = lane & 15, q8 = quad * 8;
  for (int kk = 0; kk < 512; kk += 64) {
    stage256x32_w8(A + kk, NN, As[0], tid);
    stage256x32_w8(A + kk + 32, NN, As[1], tid);
    __syncthreads();
    mfma_tile(As[0], As[0], mb, nb, l16, q8, acc);
    mfma_tile(As[1], As[1], mb, nb, l16, q8, acc);
    __syncthreads();
  }
  float* gp = Gp + ((size_t)sl * BB + bz) * CC * CC;
#pragma unroll
  for (int i = 0; i < 4; i++)
#pragma unroll
    for (int j = 0; j < 4; j++)
#pragma unroll
      for (int r = 0; r < 4; r++)
        gp[(size_t)(mb + i * 16 + quad * 4 + r) * CC + nb + j * 16 + l16] =
            acc[i][j][r];
}

// reduce: G = sum_sl Gp[sl]; s = sum_nt s_part; blocks 0..63 also build WkT
__global__ __launch_bounds__(256) void reduce_kernel(const float* __restrict__ Gp,
                                                     const float* __restrict__ s_part,
                                                     const float* __restrict__ Wk,
                                                     float* __restrict__ G,
                                                     float* __restrict__ s,
                                                     float* __restrict__ WkT) {
  __shared__ float tw[32][33];
  int t = threadIdx.x, blk = blockIdx.x;
  size_t base = ((size_t)blk * 256 + t) * 4;
  float ax = 0.f, ay = 0.f, az = 0.f, aw = 0.f;
#pragma unroll 8
  for (int sl = 0; sl < NSL; sl++) {
    float4 v = *(const float4*)&Gp[(size_t)sl * (BB * CC * CC) + base];
    ax += v.x; ay += v.y; az += v.z; aw += v.w;
  }
  float4 o; o.x = ax; o.y = ay; o.z = az; o.w = aw;
  *(float4*)&G[base] = o;
  if (blk < BB) {
    float a = 0.f;
#pragma unroll 8
    for (int nt = 0; nt < 256; nt++) a += s_part[((size_t)blk * 256 + nt) * CC + t];
    s[blk * CC + t] = a;
  }
  // Wk transpose: 64 blocks handle the 8x8 grid of 32x32 tiles
  if (blk < 64) {
    int tr = blk >> 3, tc = blk & 7;
    int r = t >> 5, c = t & 31;
#pragma unroll
    for (int i = 0; i < 4; i++)
      tw[r + i * 8][c] = Wk[(size_t)(tr * 32 + r + i * 8) * CC + tc * 32 + c];
    __syncthreads();
#pragma unroll
    for (int i = 0; i < 4; i++)
      WkT[(size_t)(tc * 32 + r + i * 8) * CC + tr * 32 + c] = tw[c][r + i * 8];
  }
}

// mid v3: per block (4 o-rows, b), 512 threads / 8 waves.
// R = Wq G + bq (x) s ; E = R WkT + u' (x) bk ; softmax ; Mv = att Wv ; bo = att.bv
__global__ __launch_bounds__(512) void mid_kernel(
    const float* __restrict__ G, const float* __restrict__ s,
    const float* __restrict__ Wq, const float* __restrict__ WkT,
    const float* __restrict__ Wv,
    const float* __restrict__ bq, const float* __restrict__ bk,
    const float* __restrict__ bv,
    u16* __restrict__ Mvb, float* __restrict__ bo) {
  __shared__ float sS[CC];
  __shared__ float wqS[4][CC];
  __shared__ float rS[4][CC];
  __shared__ float attS[4][CC];
  __shared__ float part[4][8][CC];  // [row][wave][col]
  __shared__ float redA[4][4], redB[4][4], redC[4][4], redD[4][4];
  int t = threadIdx.x;
  int o0 = blockIdx.x * 4, b = blockIdx.y;
  int wv = t >> 6, ln = t & 63;
  int col = t & 255;
  int row_a = t >> 8, row_b = row_a + 2;
  int c4 = ln << 2;
  int d0 = wv << 5;
  if (t < CC) sS[t] = s[b * CC + t];
  {
    const float* wqsrc = Wq + (size_t)o0 * CC;
    ((float*)wqS)[t] = wqsrc[t];
    ((float*)wqS)[t + 512] = wqsrc[t + 512];
  }
  __syncthreads();
  // u'[r] = Wq[o0+r,:].s + N*bq[o0+r]  (wave covers 64 distinct cols)
  float pa = wqS[row_a][col] * sS[col];
  float pb = wqS[row_b][col] * sS[col];
#pragma unroll
  for (int d = 32; d > 0; d >>= 1) {
    pa += __shfl_xor(pa, d, 64);
    pb += __shfl_xor(pb, d, 64);
  }
  if (ln == 0) { redA[row_a][wv & 3] = pa; redA[row_b][wv & 3] = pb; }
  __syncthreads();
  float up_a = redA[row_a][0] + redA[row_a][1] + redA[row_a][2] + redA[row_a][3] +
               16384.f * bq[o0 + row_a];
  float up_b = redA[row_b][0] + redA[row_b][1] + redA[row_b][2] + redA[row_b][3] +
               16384.f * bq[o0 + row_b];
  const float* Gb = G + (size_t)b * CC * CC;
  // ---- R partials: wave wv covers d in [d0, d0+32); lane covers 4 cols
  {
    f32x4 va[4] = {};
    const float* gp = Gb + (size_t)d0 * CC + c4;
#pragma unroll 8
    for (int i = 0; i < 32; i++) {
      f32x4 g4 = *(const f32x4*)(gp + (size_t)i * CC);
      float w0 = wqS[0][d0 + i], w1 = wqS[1][d0 + i];
      float w2 = wqS[2][d0 + i], w3 = wqS[3][d0 + i];
      va[0] += g4 * w0; va[1] += g4 * w1; va[2] += g4 * w2; va[3] += g4 * w3;
    }
#pragma unroll
    for (int r = 0; r < 4; r++) *(f32x4*)&part[r][wv][c4] = va[r];
  }
  __syncthreads();
  {
    float r_a = bq[o0 + row_a] * sS[col];
    float r_b = bq[o0 + row_b] * sS[col];
#pragma unroll
    for (int w = 0; w < 8; w++) { r_a += part[row_a][w][col]; r_b += part[row_b][w][col]; }
    rS[row_a][col] = r_a;
    rS[row_b][col] = r_b;
  }
  __syncthreads();
  // ---- E partials: wave covers c-range; lane covers 4 p via WkT float4 rows
  {
    f32x4 ve[4] = {};
    const float* wkp = WkT + (size_t)d0 * CC + c4;
#pragma unroll 8
    for (int i = 0; i < 32; i++) {
      f32x4 w4 = *(const f32x4*)(wkp + (size_t)i * CC);
      float r0 = rS[0][d0 + i], r1 = rS[1][d0 + i];
      float r2 = rS[2][d0 + i], r3 = rS[3][d0 + i];
      ve[0] += w4 * r0; ve[1] += w4 * r1; ve[2] += w4 * r2; ve[3] += w4 * r3;
    }
#pragma unroll
    for (int r = 0; r < 4; r++) *(f32x4*)&part[r][wv][c4] = ve[r];
  }
  __syncthreads();
  float bkc = bk[col];
  float e_a = up_a * bkc, e_b = up_b * bkc;
#pragma unroll
  for (int w = 0; w < 8; w++) { e_a += part[row_a][w][col]; e_b += part[row_b][w][col]; }
  e_a *= 0.0078125f;
  e_b *= 0.0078125f;
  // softmax over 256 p per row
  float m_a = e_a, m_b = e_b;
#pragma unroll
  for (int d = 32; d > 0; d >>= 1) {
    m_a = fmaxf(m_a, __shfl_xor(m_a, d, 64));
    m_b = fmaxf(m_b, __shfl_xor(m_b, d, 64));
  }
  if (ln == 0) { redB[row_a][wv & 3] = m_a; redB[row_b][wv & 3] = m_b; }
  __syncthreads();
  m_a = fmaxf(fmaxf(redB[row_a][0], redB[row_a][1]), fmaxf(redB[row_a][2], redB[row_a][3]));
  m_b = fmaxf(fmaxf(redB[row_b][0], redB[row_b][1]), fmaxf(redB[row_b][2], redB[row_b][3]));
  e_a = __expf(e_a - m_a);
  e_b = __expf(e_b - m_b);
  float s_a = e_a, s_b = e_b;
#pragma unroll
  for (int d = 32; d > 0; d >>= 1) {
    s_a += __shfl_xor(s_a, d, 64);
    s_b += __shfl_xor(s_b, d, 64);
  }
  if (ln == 0) { redC[row_a][wv & 3] = s_a; redC[row_b][wv & 3] = s_b; }
  __syncthreads();
  float inv_a = 1.f / (redC[row_a][0] + redC[row_a][1] + redC[row_a][2] + redC[row_a][3]);
  float inv_b = 1.f / (redC[row_b][0] + redC[row_b][1] + redC[row_b][2] + redC[row_b][3]);
  float at_a = e_a * inv_a, at_b = e_b * inv_b;
  attS[row_a][col] = at_a;
  attS[row_b][col] = at_b;
  // bo partials
  float bvc = bv[col];
  float ba = at_a * bvc, bb = at_b * bvc;
#pragma unroll
  for (int d = 32; d > 0; d >>= 1) {
    ba += __shfl_xor(ba, d, 64);
    bb += __shfl_xor(bb, d, 64);
  }
  if (ln == 0) { redD[row_a][wv & 3] = ba; redD[row_b][wv & 3] = bb; }
  __syncthreads();  // also publishes attS for the Mv loop
  if (t < 4) bo[b * CC + o0 + t] = redD[t][0] + redD[t][1] + redD[t][2] + redD[t][3];
  // ---- Mv partials: wave covers d-range; lane covers 4 c' via Wv float4 rows
  {
    f32x4 vm[4] = {};
    const float* wp = Wv + (size_t)d0 * CC + c4;
#pragma unroll 8
    for (int i = 0; i < 32; i++) {
      f32x4 w4 = *(const f32x4*)(wp + (size_t)i * CC);
      float a0 = attS[0][d0 + i], a1 = attS[1][d0 + i];
      float a2 = attS[2][d0 + i], a3 = attS[3][d0 + i];
      vm[0] += w4 * a0; vm[1] += w4 * a1; vm[2] += w4 * a2; vm[3] += w4 * a3;
    }
#pragma unroll
    for (int r = 0; r < 4; r++) *(f32x4*)&part[r][wv][c4] = vm[r];
  }
  __syncthreads();
  float mv_a = 0.f, mv_b = 0.f;
#pragma unroll
  for (int w = 0; w < 8; w++) { mv_a += part[row_a][w][col]; mv_b += part[row_b][w][col]; }
  Mvb[((size_t)b * CC + o0 + row_a) * CC + col] = f2bf(mv_a);
  Mvb[((size_t)b * CC + o0 + row_b) * CC + col] = f2bf(mv_b);
}

// out[b][c][n] = sum_c' Mv[c][c'] x[c'][n] + bo[c] + x[c][n]
// v3: full-C tile 256(c) x 256(n) per block, 8 waves as 4(m)x2(n) of 64x128
// wave tiles -> xbT read exactly once chip-wide (was 2x); staged bytes per
// output halved. float4 LDS-restage epilogue kept from v2.
__global__ __launch_bounds__(512) void out_kernel(const u16* __restrict__ Mvb,
                                                  const u16* __restrict__ xbT,
                                                  const float* __restrict__ bo,
                                                  const float* __restrict__ x,
                                                  float* __restrict__ out) {
  __shared__ union {
    struct { u16 As[2][256 * 32]; u16 Bs[2][256 * 32]; } st;
    float scr[8][64][20];
  } sm;
  int tid = threadIdx.x;
  int n0 = blockIdx.x * 256, bz = blockIdx.y;
  const u16* A = Mvb + (size_t)bz * CC * CC;
  const u16* Bt = xbT + ((size_t)bz * NN + n0) * CC;
  f32x4 acc[4][8] = {};
  int wave = tid >> 6, lane = tid & 63;
  int mb = (wave & 3) * 64, nb = (wave >> 2) * 128;
  int quad = lane >> 4, l16 = lane & 15, q8 = quad * 8;
  for (int kk = 0; kk < CC; kk += 64) {
    stage256x32_w8(A + kk, CC, sm.st.As[0], tid);
    stage256x32_w8(A + kk + 32, CC, sm.st.As[1], tid);
    stage256x32_w8(Bt + kk, CC, sm.st.Bs[0], tid);
    stage256x32_w8(Bt + kk + 32, CC, sm.st.Bs[1], tid);
    __syncthreads();
    mfma_tile48(sm.st.As[0], sm.st.Bs[0], mb, nb, l16, q8, acc);
    mfma_tile48(sm.st.As[1], sm.st.Bs[1], mb, nb, l16, q8, acc);
    __syncthreads();
  }
  // epilogue: wave-local acc transpose through LDS, then float4 streaming
  int l4 = lane >> 2;   // row within 16
  int cgl = lane & 3;   // colgroup (4 floats)
  float bc[4];
#pragma unroll
  for (int kq = 0; kq < 4; kq++) bc[kq] = bo[bz * CC + mb + kq * 16 + l4];
#pragma unroll
  for (int j = 0; j < 8; j++) {
#pragma unroll
    for (int i = 0; i < 4; i++)
#pragma unroll
      for (int r = 0; r < 4; r++)
        sm.scr[wave][i * 16 + quad * 4 + r][l16] = acc[i][j][r];
    // wave-private scratch; in-order LDS + compiler waitcnts give consistency
#pragma unroll
    for (int kq = 0; kq < 4; kq++) {
      int rloc = kq * 16 + l4;
      f32x4 v4 = *(const f32x4*)&sm.scr[wave][rloc][cgl * 4];
      int cg = mb + rloc;
      int ng = n0 + nb + j * 16 + cgl * 4;
      size_t idx = ((size_t)bz * CC + cg) * NN + ng;
      float4 xv = *(const float4*)&x[idx];
      float4 o4;
      o4.x = v4[0] + bc[kq] + xv.x;
      o4.y = v4[1] + bc[kq] + xv.y;
      o4.z = v4[2] + bc[kq] + xv.z;
      o4.w = v4[3] + bc[kq] + xv.w;
      *(float4*)&out[idx] = o4;
    }
  }
}

extern "C" void kernel_launch(void* const* d_in, const int* in_sizes, int n_in,
                              void* d_out, int out_size, void* d_ws, size_t ws_size,
                              hipStream_t stream) {
  (void)in_sizes; (void)n_in; (void)out_size; (void)ws_size;
  const float* x = (const float*)d_in[0];
  const float* wq = (const float*)d_in[1];
  const float* bq = (const float*)d_in[2];
  const float* wk = (const float*)d_in[3];
  const float* bk = (const float*)d_in[4];
  const float* wv = (const float*)d_in[5];
  const float* bv = (const float*)d_in[6];
  float* out = (float*)d_out;

  char* ws = (char*)d_ws;
  u16* xb      = (u16*)(ws + 0);            // 32 MiB  (B,C,N) bf16
  u16* xbT     = (u16*)(ws + 33554432);     // 32 MiB  (B,N,C) bf16
  float* Gp    = (float*)(ws + 67108864);   // 32 MiB  (NSL,B,C,C) fp32 partials
  float* G     = (float*)(ws + 100663296);  // 1 MiB
  float* s_prt = (float*)(ws + 101711872);  // 1 MiB   (B,256,C)
  float* s     = (float*)(ws + 102760448);  // 4 KiB
  u16* Mvb     = (u16*)(ws + 102764544);    // 512 KiB
  float* bo    = (float*)(ws + 103288832);  // 4 KiB
  float* WkT   = (float*)(ws + 103292928);  // 256 KiB

  prep_kernel<<<dim3(NN / 64, CC / 64, BB), 256, 0, stream>>>(x, xb, xbT, s_prt);
  gram_kernel<<<dim3(2, NSL, BB), 512, 0, stream>>>(xb, Gp);
  reduce_kernel<<<256, 256, 0, stream>>>(Gp, s_prt, wk, G, s, WkT);
  mid_kernel<<<dim3(CC / 4, BB), 512, 0, stream>>>(G, s, wq, WkT, wv, bq, bk, bv, Mvb, bo);
  out_kernel<<<dim3(NN / 256, BB), 512, 0, stream>>>(Mvb, xbT, bo, x, out);
}

// Round 5
// 207.160 us; speedup vs baseline: 1.0824x; 1.0824x over previous
//
#include <hip/hip_runtime.h>
#include <stdint.h>

#define BB 4
#define CC 256
#define NN 16384  // 128*128
#define NSL 32    // gram split-K slices
#define NT 128    // prep n-tiles (NN / 128)

typedef unsigned short u16;
typedef __attribute__((ext_vector_type(8))) __bf16 bf16x8;
typedef __attribute__((ext_vector_type(4))) float f32x4;

// fp32 -> bf16 round-to-nearest-even
__device__ __forceinline__ u16 f2bf(float f) {
  union { float f; uint32_t u; } c;
  c.f = f;
  uint32_t u = c.u;
  return (u16)((u + 0x7fffu + ((u >> 16) & 1u)) >> 16);
}

// async global->LDS, 16 bytes per lane (global_load_lds_dwordx4)
__device__ __forceinline__ void g2l16(const u16* g, u16* l) {
  __builtin_amdgcn_global_load_lds((__attribute__((address_space(1))) void*)g,
                                   (__attribute__((address_space(3))) void*)l, 16, 0, 0);
}

// 512-thread block: stage 256x32 panel (row stride `stride`) into lds[256*32]
__device__ __forceinline__ void stage256x32_w8(const u16* src, int stride, u16* lds, int tid) {
  int r = tid >> 2;
  int c = (tid & 3) << 3;
  g2l16(src + (size_t)r * stride + c, lds + r * 32 + c);
  g2l16(src + (size_t)(r + 128) * stride + c, lds + (r + 128) * 32 + c);
}

// 512-thread block: stage 128x32 panel (one g2l16/thread)
__device__ __forceinline__ void stage128x32_w8(const u16* src, int stride, u16* lds, int tid) {
  int r = tid >> 2;
  int c = (tid & 3) << 3;
  g2l16(src + (size_t)r * stride + c, lds + r * 32 + c);
}

// one 32-deep k-step: 16 MFMAs on a 64x64 per-wave tile (A,B may alias)
__device__ __forceinline__ void mfma_tile(const u16* As, const u16* Bs, int mb, int nb,
                                          int l16, int q8, f32x4 acc[4][4]) {
  bf16x8 af[4], bf[4];
#pragma unroll
  for (int i = 0; i < 4; i++) af[i] = *(const bf16x8*)&As[(mb + i * 16 + l16) * 32 + q8];
#pragma unroll
  for (int i = 0; i < 4; i++) bf[i] = *(const bf16x8*)&Bs[(nb + i * 16 + l16) * 32 + q8];
#pragma unroll
  for (int i = 0; i < 4; i++)
#pragma unroll
    for (int j = 0; j < 4; j++)
      acc[i][j] = __builtin_amdgcn_mfma_f32_16x16x32_bf16(af[i], bf[j], acc[i][j], 0, 0, 0);
}

// prep v2: x fp32 (B,C,N) -> xb bf16 (B,C,N), xbT bf16 (B,N,C),
// s_part[b][ntile][c] partial row sums. Tile 64(c) x 128(n): x reads are
// 512 B/row chunks (was 256 B) for better HBM burst efficiency.
__global__ __launch_bounds__(256) void prep_kernel(const float* __restrict__ x,
                                                   u16* __restrict__ xb,
                                                   u16* __restrict__ xbT,
                                                   float* __restrict__ s_part) {
  __shared__ float t[64][129];
  __shared__ float rs[64][4];
  int n0 = blockIdx.x * 128, c0 = blockIdx.y * 64, bz = blockIdx.z;
  int tid = threadIdx.x;
  int rl = tid >> 5;            // 0..7   (8 c-rows per pass)
  int ql = (tid & 31) * 4;      // 0..124 (32 lanes cover 128 n)
  const float* xs = x + ((size_t)bz * CC + c0) * NN + n0;
  u16* xbp = xb + ((size_t)bz * CC + c0) * NN + n0;
#pragma unroll
  for (int cc = rl; cc < 64; cc += 8) {
    float4 v = *(const float4*)&xs[(size_t)cc * NN + ql];
    t[cc][ql] = v.x; t[cc][ql + 1] = v.y; t[cc][ql + 2] = v.z; t[cc][ql + 3] = v.w;
    union { u16 h[4]; uint2 u; } pk;
    pk.h[0] = f2bf(v.x); pk.h[1] = f2bf(v.y); pk.h[2] = f2bf(v.z); pk.h[3] = f2bf(v.w);
    *(uint2*)&xbp[(size_t)cc * NN + ql] = pk.u;
  }
  __syncthreads();
  {
    int r = tid >> 2, q = tid & 3;
    float p = 0.f;
#pragma unroll
    for (int i = 0; i < 32; i++) p += t[r][q * 32 + i];
    rs[r][q] = p;
  }
  u16* od = xbT + ((size_t)bz * NN + n0) * CC + c0;
  int rt = tid >> 4, qt = (tid & 15) * 4;  // 16 n-rows/pass, 16 lanes cover 64 c
#pragma unroll
  for (int nn = rt; nn < 128; nn += 16) {
    union { u16 h[4]; uint2 u; } pk;
    pk.h[0] = f2bf(t[qt][nn]); pk.h[1] = f2bf(t[qt + 1][nn]);
    pk.h[2] = f2bf(t[qt + 2][nn]); pk.h[3] = f2bf(t[qt + 3][nn]);
    *(uint2*)&od[(size_t)nn * CC + qt] = pk.u;
  }
  __syncthreads();
  if (tid < 64)
    s_part[((size_t)bz * NT + blockIdx.x) * CC + c0 + tid] =
        rs[tid][0] + rs[tid][1] + rs[tid][2] + rs[tid][3];
}

// Gp[sl][b] = partial xb xb^T over K-slice sl (plain stores, NO atomics)
// symmetric-operand panel sharing: one 256x32 panel per block serves as both
// A and B. Block = 256(c) x 128(d), 8 waves (4x2 of 64x64).
__global__ __launch_bounds__(512) void gram_kernel(const u16* __restrict__ xb,
                                                   float* __restrict__ Gp) {
  __shared__ u16 As[2][256 * 32];
  int tid = threadIdx.x;
  int d0 = blockIdx.x * 128;
  int sl = blockIdx.y, bz = blockIdx.z;
  const u16* A = xb + (size_t)bz * CC * NN + sl * 512;
  f32x4 acc[4][4] = {};
  int wave = tid >> 6, lane = tid & 63;
  int mb = (wave & 3) * 64, nb = d0 + (wave >> 2) * 64;
  int quad = lane >> 4, l16 = lane & 15, q8 = quad * 8;
  for (int kk = 0; kk < 512; kk += 64) {
    stage256x32_w8(A + kk, NN, As[0], tid);
    stage256x32_w8(A + kk + 32, NN, As[1], tid);
    __syncthreads();
    mfma_tile(As[0], As[0], mb, nb, l16, q8, acc);
    mfma_tile(As[1], As[1], mb, nb, l16, q8, acc);
    __syncthreads();
  }
  float* gp = Gp + ((size_t)sl * BB + bz) * CC * CC;
#pragma unroll
  for (int i = 0; i < 4; i++)
#pragma unroll
    for (int j = 0; j < 4; j++)
#pragma unroll
      for (int r = 0; r < 4; r++)
        gp[(size_t)(mb + i * 16 + quad * 4 + r) * CC + nb + j * 16 + l16] =
            acc[i][j][r];
}

// reduce: G = sum_sl Gp[sl]; s = sum_nt s_part; blocks 0..63 also build WkT
__global__ __launch_bounds__(256) void reduce_kernel(const float* __restrict__ Gp,
                                                     const float* __restrict__ s_part,
                                                     const float* __restrict__ Wk,
                                                     float* __restrict__ G,
                                                     float* __restrict__ s,
                                                     float* __restrict__ WkT) {
  __shared__ float tw[32][33];
  int t = threadIdx.x, blk = blockIdx.x;
  size_t base = ((size_t)blk * 256 + t) * 4;
  float ax = 0.f, ay = 0.f, az = 0.f, aw = 0.f;
#pragma unroll 8
  for (int sl = 0; sl < NSL; sl++) {
    float4 v = *(const float4*)&Gp[(size_t)sl * (BB * CC * CC) + base];
    ax += v.x; ay += v.y; az += v.z; aw += v.w;
  }
  float4 o; o.x = ax; o.y = ay; o.z = az; o.w = aw;
  *(float4*)&G[base] = o;
  if (blk < BB) {
    float a = 0.f;
#pragma unroll 8
    for (int nt = 0; nt < NT; nt++) a += s_part[((size_t)blk * NT + nt) * CC + t];
    s[blk * CC + t] = a;
  }
  // Wk transpose: 64 blocks handle the 8x8 grid of 32x32 tiles
  if (blk < 64) {
    int tr = blk >> 3, tc = blk & 7;
    int r = t >> 5, c = t & 31;
#pragma unroll
    for (int i = 0; i < 4; i++)
      tw[r + i * 8][c] = Wk[(size_t)(tr * 32 + r + i * 8) * CC + tc * 32 + c];
    __syncthreads();
#pragma unroll
    for (int i = 0; i < 4; i++)
      WkT[(size_t)(tc * 32 + r + i * 8) * CC + tr * 32 + c] = tw[c][r + i * 8];
  }
}

// mid v3: per block (4 o-rows, b), 512 threads / 8 waves.
// R = Wq G + bq (x) s ; E = R WkT + u' (x) bk ; softmax ; Mv = att Wv ; bo = att.bv
__global__ __launch_bounds__(512) void mid_kernel(
    const float* __restrict__ G, const float* __restrict__ s,
    const float* __restrict__ Wq, const float* __restrict__ WkT,
    const float* __restrict__ Wv,
    const float* __restrict__ bq, const float* __restrict__ bk,
    const float* __restrict__ bv,
    u16* __restrict__ Mvb, float* __restrict__ bo) {
  __shared__ float sS[CC];
  __shared__ float wqS[4][CC];
  __shared__ float rS[4][CC];
  __shared__ float attS[4][CC];
  __shared__ float part[4][8][CC];  // [row][wave][col]
  __shared__ float redA[4][4], redB[4][4], redC[4][4], redD[4][4];
  int t = threadIdx.x;
  int o0 = blockIdx.x * 4, b = blockIdx.y;
  int wv = t >> 6, ln = t & 63;
  int col = t & 255;
  int row_a = t >> 8, row_b = row_a + 2;
  int c4 = ln << 2;
  int d0 = wv << 5;
  if (t < CC) sS[t] = s[b * CC + t];
  {
    const float* wqsrc = Wq + (size_t)o0 * CC;
    ((float*)wqS)[t] = wqsrc[t];
    ((float*)wqS)[t + 512] = wqsrc[t + 512];
  }
  __syncthreads();
  // u'[r] = Wq[o0+r,:].s + N*bq[o0+r]  (wave covers 64 distinct cols)
  float pa = wqS[row_a][col] * sS[col];
  float pb = wqS[row_b][col] * sS[col];
#pragma unroll
  for (int d = 32; d > 0; d >>= 1) {
    pa += __shfl_xor(pa, d, 64);
    pb += __shfl_xor(pb, d, 64);
  }
  if (ln == 0) { redA[row_a][wv & 3] = pa; redA[row_b][wv & 3] = pb; }
  __syncthreads();
  float up_a = redA[row_a][0] + redA[row_a][1] + redA[row_a][2] + redA[row_a][3] +
               16384.f * bq[o0 + row_a];
  float up_b = redA[row_b][0] + redA[row_b][1] + redA[row_b][2] + redA[row_b][3] +
               16384.f * bq[o0 + row_b];
  const float* Gb = G + (size_t)b * CC * CC;
  // ---- R partials: wave wv covers d in [d0, d0+32); lane covers 4 cols
  {
    f32x4 va[4] = {};
    const float* gp = Gb + (size_t)d0 * CC + c4;
#pragma unroll 8
    for (int i = 0; i < 32; i++) {
      f32x4 g4 = *(const f32x4*)(gp + (size_t)i * CC);
      float w0 = wqS[0][d0 + i], w1 = wqS[1][d0 + i];
      float w2 = wqS[2][d0 + i], w3 = wqS[3][d0 + i];
      va[0] += g4 * w0; va[1] += g4 * w1; va[2] += g4 * w2; va[3] += g4 * w3;
    }
#pragma unroll
    for (int r = 0; r < 4; r++) *(f32x4*)&part[r][wv][c4] = va[r];
  }
  __syncthreads();
  {
    float r_a = bq[o0 + row_a] * sS[col];
    float r_b = bq[o0 + row_b] * sS[col];
#pragma unroll
    for (int w = 0; w < 8; w++) { r_a += part[row_a][w][col]; r_b += part[row_b][w][col]; }
    rS[row_a][col] = r_a;
    rS[row_b][col] = r_b;
  }
  __syncthreads();
  // ---- E partials: wave covers c-range; lane covers 4 p via WkT float4 rows
  {
    f32x4 ve[4] = {};
    const float* wkp = WkT + (size_t)d0 * CC + c4;
#pragma unroll 8
    for (int i = 0; i < 32; i++) {
      f32x4 w4 = *(const f32x4*)(wkp + (size_t)i * CC);
      float r0 = rS[0][d0 + i], r1 = rS[1][d0 + i];
      float r2 = rS[2][d0 + i], r3 = rS[3][d0 + i];
      ve[0] += w4 * r0; ve[1] += w4 * r1; ve[2] += w4 * r2; ve[3] += w4 * r3;
    }
#pragma unroll
    for (int r = 0; r < 4; r++) *(f32x4*)&part[r][wv][c4] = ve[r];
  }
  __syncthreads();
  float bkc = bk[col];
  float e_a = up_a * bkc, e_b = up_b * bkc;
#pragma unroll
  for (int w = 0; w < 8; w++) { e_a += part[row_a][w][col]; e_b += part[row_b][w][col]; }
  e_a *= 0.0078125f;
  e_b *= 0.0078125f;
  // softmax over 256 p per row
  float m_a = e_a, m_b = e_b;
#pragma unroll
  for (int d = 32; d > 0; d >>= 1) {
    m_a = fmaxf(m_a, __shfl_xor(m_a, d, 64));
    m_b = fmaxf(m_b, __shfl_xor(m_b, d, 64));
  }
  if (ln == 0) { redB[row_a][wv & 3] = m_a; redB[row_b][wv & 3] = m_b; }
  __syncthreads();
  m_a = fmaxf(fmaxf(redB[row_a][0], redB[row_a][1]), fmaxf(redB[row_a][2], redB[row_a][3]));
  m_b = fmaxf(fmaxf(redB[row_b][0], redB[row_b][1]), fmaxf(redB[row_b][2], redB[row_b][3]));
  e_a = __expf(e_a - m_a);
  e_b = __expf(e_b - m_b);
  float s_a = e_a, s_b = e_b;
#pragma unroll
  for (int d = 32; d > 0; d >>= 1) {
    s_a += __shfl_xor(s_a, d, 64);
    s_b += __shfl_xor(s_b, d, 64);
  }
  if (ln == 0) { redC[row_a][wv & 3] = s_a; redC[row_b][wv & 3] = s_b; }
  __syncthreads();
  float inv_a = 1.f / (redC[row_a][0] + redC[row_a][1] + redC[row_a][2] + redC[row_a][3]);
  float inv_b = 1.f / (redC[row_b][0] + redC[row_b][1] + redC[row_b][2] + redC[row_b][3]);
  float at_a = e_a * inv_a, at_b = e_b * inv_b;
  attS[row_a][col] = at_a;
  attS[row_b][col] = at_b;
  // bo partials
  float bvc = bv[col];
  float ba = at_a * bvc, bb = at_b * bvc;
#pragma unroll
  for (int d = 32; d > 0; d >>= 1) {
    ba += __shfl_xor(ba, d, 64);
    bb += __shfl_xor(bb, d, 64);
  }
  if (ln == 0) { redD[row_a][wv & 3] = ba; redD[row_b][wv & 3] = bb; }
  __syncthreads();  // also publishes attS for the Mv loop
  if (t < 4) bo[b * CC + o0 + t] = redD[t][0] + redD[t][1] + redD[t][2] + redD[t][3];
  // ---- Mv partials: wave covers d-range; lane covers 4 c' via Wv float4 rows
  {
    f32x4 vm[4] = {};
    const float* wp = Wv + (size_t)d0 * CC + c4;
#pragma unroll 8
    for (int i = 0; i < 32; i++) {
      f32x4 w4 = *(const f32x4*)(wp + (size_t)i * CC);
      float a0 = attS[0][d0 + i], a1 = attS[1][d0 + i];
      float a2 = attS[2][d0 + i], a3 = attS[3][d0 + i];
      vm[0] += w4 * a0; vm[1] += w4 * a1; vm[2] += w4 * a2; vm[3] += w4 * a3;
    }
#pragma unroll
    for (int r = 0; r < 4; r++) *(f32x4*)&part[r][wv][c4] = vm[r];
  }
  __syncthreads();
  float mv_a = 0.f, mv_b = 0.f;
#pragma unroll
  for (int w = 0; w < 8; w++) { mv_a += part[row_a][w][col]; mv_b += part[row_b][w][col]; }
  Mvb[((size_t)b * CC + o0 + row_a) * CC + col] = f2bf(mv_a);
  Mvb[((size_t)b * CC + o0 + row_b) * CC + col] = f2bf(mv_b);
}

// out v4: 256(c) x 128(n) tile, 8 waves as 4(c)x2(n) of 64x64, acc[4][4].
// LDS 48 KB + launch_bounds(512,4) (VGPR<=128) -> 2 blocks/CU so cross-block
// wave overlap hides the staging barrier drains (was 1 block/CU, fully
// exposed). xbT read exactly once; Mvb re-reads are L2-resident (512 KB).
// float4 LDS-restage epilogue kept.
__global__ __launch_bounds__(512, 4) void out_kernel(const u16* __restrict__ Mvb,
                                                     const u16* __restrict__ xbT,
                                                     const float* __restrict__ bo,
                                                     const float* __restrict__ x,
                                                     float* __restrict__ out) {
  __shared__ union {
    struct { u16 As[2][256 * 32]; u16 Bs[2][128 * 32]; } st;  // 48 KB
    float scr[8][64][20];                                     // 40 KB
  } sm;
  int tid = threadIdx.x;
  int n0 = blockIdx.x * 128, bz = blockIdx.y;
  const u16* A = Mvb + (size_t)bz * CC * CC;
  const u16* Bt = xbT + ((size_t)bz * NN + n0) * CC;
  f32x4 acc[4][4] = {};
  int wave = tid >> 6, lane = tid & 63;
  int mb = (wave & 3) * 64, nb = (wave >> 2) * 64;
  int quad = lane >> 4, l16 = lane & 15, q8 = quad * 8;
  for (int kk = 0; kk < CC; kk += 64) {
    stage256x32_w8(A + kk, CC, sm.st.As[0], tid);
    stage256x32_w8(A + kk + 32, CC, sm.st.As[1], tid);
    stage128x32_w8(Bt + kk, CC, sm.st.Bs[0], tid);
    stage128x32_w8(Bt + kk + 32, CC, sm.st.Bs[1], tid);
    __syncthreads();
    mfma_tile(sm.st.As[0], sm.st.Bs[0], mb, nb, l16, q8, acc);
    mfma_tile(sm.st.As[1], sm.st.Bs[1], mb, nb, l16, q8, acc);
    __syncthreads();
  }
  // epilogue: wave-local acc transpose through LDS, then float4 streaming
  int l4 = lane >> 2;   // row within 16
  int cgl = lane & 3;   // colgroup (4 floats)
  float bc[4];
#pragma unroll
  for (int kq = 0; kq < 4; kq++) bc[kq] = bo[bz * CC + mb + kq * 16 + l4];
#pragma unroll
  for (int j = 0; j < 4; j++) {
#pragma unroll
    for (int i = 0; i < 4; i++)
#pragma unroll
      for (int r = 0; r < 4; r++)
        sm.scr[wave][i * 16 + quad * 4 + r][l16] = acc[i][j][r];
    // wave-private scratch; in-order LDS + compiler waitcnts give consistency
#pragma unroll
    for (int kq = 0; kq < 4; kq++) {
      int rloc = kq * 16 + l4;
      f32x4 v4 = *(const f32x4*)&sm.scr[wave][rloc][cgl * 4];
      int cg = mb + rloc;
      int ng = n0 + nb + j * 16 + cgl * 4;
      size_t idx = ((size_t)bz * CC + cg) * NN + ng;
      float4 xv = *(const float4*)&x[idx];
      float4 o4;
      o4.x = v4[0] + bc[kq] + xv.x;
      o4.y = v4[1] + bc[kq] + xv.y;
      o4.z = v4[2] + bc[kq] + xv.z;
      o4.w = v4[3] + bc[kq] + xv.w;
      *(float4*)&out[idx] = o4;
    }
  }
}

extern "C" void kernel_launch(void* const* d_in, const int* in_sizes, int n_in,
                              void* d_out, int out_size, void* d_ws, size_t ws_size,
                              hipStream_t stream) {
  (void)in_sizes; (void)n_in; (void)out_size; (void)ws_size;
  const float* x = (const float*)d_in[0];
  const float* wq = (const float*)d_in[1];
  const float* bq = (const float*)d_in[2];
  const float* wk = (const float*)d_in[3];
  const float* bk = (const float*)d_in[4];
  const float* wv = (const float*)d_in[5];
  const float* bv = (const float*)d_in[6];
  float* out = (float*)d_out;

  char* ws = (char*)d_ws;
  u16* xb      = (u16*)(ws + 0);            // 32 MiB  (B,C,N) bf16
  u16* xbT     = (u16*)(ws + 33554432);     // 32 MiB  (B,N,C) bf16
  float* Gp    = (float*)(ws + 67108864);   // 32 MiB  (NSL,B,C,C) fp32 partials
  float* G     = (float*)(ws + 100663296);  // 1 MiB
  float* s_prt = (float*)(ws + 101711872);  // 512 KiB (B,NT,C)
  float* s     = (float*)(ws + 102760448);  // 4 KiB
  u16* Mvb     = (u16*)(ws + 102764544);    // 512 KiB
  float* bo    = (float*)(ws + 103288832);  // 4 KiB
  float* WkT   = (float*)(ws + 103292928);  // 256 KiB

  prep_kernel<<<dim3(NN / 128, CC / 64, BB), 256, 0, stream>>>(x, xb, xbT, s_prt);
  gram_kernel<<<dim3(2, NSL, BB), 512, 0, stream>>>(xb, Gp);
  reduce_kernel<<<256, 256, 0, stream>>>(Gp, s_prt, wk, G, s, WkT);
  mid_kernel<<<dim3(CC / 4, BB), 512, 0, stream>>>(G, s, wq, WkT, wv, bq, bk, bv, Mvb, bo);
  out_kernel<<<dim3(NN / 128, BB), 512, 0, stream>>>(Mvb, xbT, bo, x, out);
}

// Round 6
// 205.371 us; speedup vs baseline: 1.0919x; 1.0087x over previous
//
#include <hip/hip_runtime.h>
#include <stdint.h>

#define BB 4
#define CC 256
#define NN 16384  // 128*128
#define NSL 32    // gram split-K slices
#define NT 128    // prep n-tiles (NN / 128)

typedef unsigned short u16;
typedef __attribute__((ext_vector_type(8))) __bf16 bf16x8;
typedef __attribute__((ext_vector_type(4))) float f32x4;

// fp32 -> bf16 round-to-nearest-even
__device__ __forceinline__ u16 f2bf(float f) {
  union { float f; uint32_t u; } c;
  c.f = f;
  uint32_t u = c.u;
  return (u16)((u + 0x7fffu + ((u >> 16) & 1u)) >> 16);
}

// async global->LDS, 16 bytes per lane (global_load_lds_dwordx4)
__device__ __forceinline__ void g2l16(const u16* g, u16* l) {
  __builtin_amdgcn_global_load_lds((__attribute__((address_space(1))) void*)g,
                                   (__attribute__((address_space(3))) void*)l, 16, 0, 0);
}

// 512-thread block: stage 256x32 panel (row stride `stride`) into lds[256*32]
__device__ __forceinline__ void stage256x32_w8(const u16* src, int stride, u16* lds, int tid) {
  int r = tid >> 2;
  int c = (tid & 3) << 3;
  g2l16(src + (size_t)r * stride + c, lds + r * 32 + c);
  g2l16(src + (size_t)(r + 128) * stride + c, lds + (r + 128) * 32 + c);
}

// 512-thread block: stage 128x32 panel (one g2l16/thread)
__device__ __forceinline__ void stage128x32_w8(const u16* src, int stride, u16* lds, int tid) {
  int r = tid >> 2;
  int c = (tid & 3) << 3;
  g2l16(src + (size_t)r * stride + c, lds + r * 32 + c);
}

// one 32-deep k-step: 16 MFMAs on a 64x64 per-wave tile (A,B may alias)
__device__ __forceinline__ void mfma_tile(const u16* As, const u16* Bs, int mb, int nb,
                                          int l16, int q8, f32x4 acc[4][4]) {
  bf16x8 af[4], bf[4];
#pragma unroll
  for (int i = 0; i < 4; i++) af[i] = *(const bf16x8*)&As[(mb + i * 16 + l16) * 32 + q8];
#pragma unroll
  for (int i = 0; i < 4; i++) bf[i] = *(const bf16x8*)&Bs[(nb + i * 16 + l16) * 32 + q8];
#pragma unroll
  for (int i = 0; i < 4; i++)
#pragma unroll
    for (int j = 0; j < 4; j++)
      acc[i][j] = __builtin_amdgcn_mfma_f32_16x16x32_bf16(af[i], bf[j], acc[i][j], 0, 0, 0);
}

// prep v2: x fp32 (B,C,N) -> xb bf16 (B,C,N), xbT bf16 (B,N,C),
// s_part[b][ntile][c] partial row sums. Tile 64(c) x 128(n).
__global__ __launch_bounds__(256) void prep_kernel(const float* __restrict__ x,
                                                   u16* __restrict__ xb,
                                                   u16* __restrict__ xbT,
                                                   float* __restrict__ s_part) {
  __shared__ float t[64][129];
  __shared__ float rs[64][4];
  int n0 = blockIdx.x * 128, c0 = blockIdx.y * 64, bz = blockIdx.z;
  int tid = threadIdx.x;
  int rl = tid >> 5;            // 0..7   (8 c-rows per pass)
  int ql = (tid & 31) * 4;      // 0..124 (32 lanes cover 128 n)
  const float* xs = x + ((size_t)bz * CC + c0) * NN + n0;
  u16* xbp = xb + ((size_t)bz * CC + c0) * NN + n0;
#pragma unroll
  for (int cc = rl; cc < 64; cc += 8) {
    float4 v = *(const float4*)&xs[(size_t)cc * NN + ql];
    t[cc][ql] = v.x; t[cc][ql + 1] = v.y; t[cc][ql + 2] = v.z; t[cc][ql + 3] = v.w;
    union { u16 h[4]; uint2 u; } pk;
    pk.h[0] = f2bf(v.x); pk.h[1] = f2bf(v.y); pk.h[2] = f2bf(v.z); pk.h[3] = f2bf(v.w);
    *(uint2*)&xbp[(size_t)cc * NN + ql] = pk.u;
  }
  __syncthreads();
  {
    int r = tid >> 2, q = tid & 3;
    float p = 0.f;
#pragma unroll
    for (int i = 0; i < 32; i++) p += t[r][q * 32 + i];
    rs[r][q] = p;
  }
  u16* od = xbT + ((size_t)bz * NN + n0) * CC + c0;
  int rt = tid >> 4, qt = (tid & 15) * 4;  // 16 n-rows/pass, 16 lanes cover 64 c
#pragma unroll
  for (int nn = rt; nn < 128; nn += 16) {
    union { u16 h[4]; uint2 u; } pk;
    pk.h[0] = f2bf(t[qt][nn]); pk.h[1] = f2bf(t[qt + 1][nn]);
    pk.h[2] = f2bf(t[qt + 2][nn]); pk.h[3] = f2bf(t[qt + 3][nn]);
    *(uint2*)&od[(size_t)nn * CC + qt] = pk.u;
  }
  __syncthreads();
  if (tid < 64)
    s_part[((size_t)bz * NT + blockIdx.x) * CC + c0 + tid] =
        rs[tid][0] + rs[tid][1] + rs[tid][2] + rs[tid][3];
}

// Gp[sl][b] = partial xb xb^T over K-slice sl (plain stores, NO atomics)
// v3: symmetric panel sharing + T3-min 2-phase pipeline: double-buffered
// 256x32 panels, next-tile STAGE issued BEFORE current MFMA, one barrier per
// BK=32 step (was stage->barrier->MFMA->barrier with zero overlap).
// K-order unchanged -> bitwise-identical Gp.
__global__ __launch_bounds__(512) void gram_kernel(const u16* __restrict__ xb,
                                                   float* __restrict__ Gp) {
  __shared__ u16 As[2][256 * 32];
  int tid = threadIdx.x;
  int d0 = blockIdx.x * 128;
  int sl = blockIdx.y, bz = blockIdx.z;
  const u16* A = xb + (size_t)bz * CC * NN + sl * 512;
  f32x4 acc[4][4] = {};
  int wave = tid >> 6, lane = tid & 63;
  int mb = (wave & 3) * 64, nb = d0 + (wave >> 2) * 64;
  int quad = lane >> 4, l16 = lane & 15, q8 = quad * 8;
  stage256x32_w8(A, NN, As[0], tid);
  __syncthreads();
  for (int t = 0; t < 16; t++) {
    if (t < 15) stage256x32_w8(A + (t + 1) * 32, NN, As[(t + 1) & 1], tid);
    mfma_tile(As[t & 1], As[t & 1], mb, nb, l16, q8, acc);
    __syncthreads();
  }
  float* gp = Gp + ((size_t)sl * BB + bz) * CC * CC;
#pragma unroll
  for (int i = 0; i < 4; i++)
#pragma unroll
    for (int j = 0; j < 4; j++)
#pragma unroll
      for (int r = 0; r < 4; r++)
        gp[(size_t)(mb + i * 16 + quad * 4 + r) * CC + nb + j * 16 + l16] =
            acc[i][j][r];
}

// reduce: G = sum_sl Gp[sl]; s = sum_nt s_part; blocks 0..63 also build WkT
__global__ __launch_bounds__(256) void reduce_kernel(const float* __restrict__ Gp,
                                                     const float* __restrict__ s_part,
                                                     const float* __restrict__ Wk,
                                                     float* __restrict__ G,
                                                     float* __restrict__ s,
                                                     float* __restrict__ WkT) {
  __shared__ float tw[32][33];
  int t = threadIdx.x, blk = blockIdx.x;
  size_t base = ((size_t)blk * 256 + t) * 4;
  float ax = 0.f, ay = 0.f, az = 0.f, aw = 0.f;
#pragma unroll 8
  for (int sl = 0; sl < NSL; sl++) {
    float4 v = *(const float4*)&Gp[(size_t)sl * (BB * CC * CC) + base];
    ax += v.x; ay += v.y; az += v.z; aw += v.w;
  }
  float4 o; o.x = ax; o.y = ay; o.z = az; o.w = aw;
  *(float4*)&G[base] = o;
  if (blk < BB) {
    float a = 0.f;
#pragma unroll 8
    for (int nt = 0; nt < NT; nt++) a += s_part[((size_t)blk * NT + nt) * CC + t];
    s[blk * CC + t] = a;
  }
  // Wk transpose: 64 blocks handle the 8x8 grid of 32x32 tiles
  if (blk < 64) {
    int tr = blk >> 3, tc = blk & 7;
    int r = t >> 5, c = t & 31;
#pragma unroll
    for (int i = 0; i < 4; i++)
      tw[r + i * 8][c] = Wk[(size_t)(tr * 32 + r + i * 8) * CC + tc * 32 + c];
    __syncthreads();
#pragma unroll
    for (int i = 0; i < 4; i++)
      WkT[(size_t)(tc * 32 + r + i * 8) * CC + tr * 32 + c] = tw[c][r + i * 8];
  }
}

// mid v3: per block (4 o-rows, b), 512 threads / 8 waves.
// R = Wq G + bq (x) s ; E = R WkT + u' (x) bk ; softmax ; Mv = att Wv ; bo = att.bv
__global__ __launch_bounds__(512) void mid_kernel(
    const float* __restrict__ G, const float* __restrict__ s,
    const float* __restrict__ Wq, const float* __restrict__ WkT,
    const float* __restrict__ Wv,
    const float* __restrict__ bq, const float* __restrict__ bk,
    const float* __restrict__ bv,
    u16* __restrict__ Mvb, float* __restrict__ bo) {
  __shared__ float sS[CC];
  __shared__ float wqS[4][CC];
  __shared__ float rS[4][CC];
  __shared__ float attS[4][CC];
  __shared__ float part[4][8][CC];  // [row][wave][col]
  __shared__ float redA[4][4], redB[4][4], redC[4][4], redD[4][4];
  int t = threadIdx.x;
  int o0 = blockIdx.x * 4, b = blockIdx.y;
  int wv = t >> 6, ln = t & 63;
  int col = t & 255;
  int row_a = t >> 8, row_b = row_a + 2;
  int c4 = ln << 2;
  int d0 = wv << 5;
  if (t < CC) sS[t] = s[b * CC + t];
  {
    const float* wqsrc = Wq + (size_t)o0 * CC;
    ((float*)wqS)[t] = wqsrc[t];
    ((float*)wqS)[t + 512] = wqsrc[t + 512];
  }
  __syncthreads();
  // u'[r] = Wq[o0+r,:].s + N*bq[o0+r]  (wave covers 64 distinct cols)
  float pa = wqS[row_a][col] * sS[col];
  float pb = wqS[row_b][col] * sS[col];
#pragma unroll
  for (int d = 32; d > 0; d >>= 1) {
    pa += __shfl_xor(pa, d, 64);
    pb += __shfl_xor(pb, d, 64);
  }
  if (ln == 0) { redA[row_a][wv & 3] = pa; redA[row_b][wv & 3] = pb; }
  __syncthreads();
  float up_a = redA[row_a][0] + redA[row_a][1] + redA[row_a][2] + redA[row_a][3] +
               16384.f * bq[o0 + row_a];
  float up_b = redA[row_b][0] + redA[row_b][1] + redA[row_b][2] + redA[row_b][3] +
               16384.f * bq[o0 + row_b];
  const float* Gb = G + (size_t)b * CC * CC;
  // ---- R partials: wave wv covers d in [d0, d0+32); lane covers 4 cols
  {
    f32x4 va[4] = {};
    const float* gp = Gb + (size_t)d0 * CC + c4;
#pragma unroll 8
    for (int i = 0; i < 32; i++) {
      f32x4 g4 = *(const f32x4*)(gp + (size_t)i * CC);
      float w0 = wqS[0][d0 + i], w1 = wqS[1][d0 + i];
      float w2 = wqS[2][d0 + i], w3 = wqS[3][d0 + i];
      va[0] += g4 * w0; va[1] += g4 * w1; va[2] += g4 * w2; va[3] += g4 * w3;
    }
#pragma unroll
    for (int r = 0; r < 4; r++) *(f32x4*)&part[r][wv][c4] = va[r];
  }
  __syncthreads();
  {
    float r_a = bq[o0 + row_a] * sS[col];
    float r_b = bq[o0 + row_b] * sS[col];
#pragma unroll
    for (int w = 0; w < 8; w++) { r_a += part[row_a][w][col]; r_b += part[row_b][w][col]; }
    rS[row_a][col] = r_a;
    rS[row_b][col] = r_b;
  }
  __syncthreads();
  // ---- E partials: wave covers c-range; lane covers 4 p via WkT float4 rows
  {
    f32x4 ve[4] = {};
    const float* wkp = WkT + (size_t)d0 * CC + c4;
#pragma unroll 8
    for (int i = 0; i < 32; i++) {
      f32x4 w4 = *(const f32x4*)(wkp + (size_t)i * CC);
      float r0 = rS[0][d0 + i], r1 = rS[1][d0 + i];
      float r2 = rS[2][d0 + i], r3 = rS[3][d0 + i];
      ve[0] += w4 * r0; ve[1] += w4 * r1; ve[2] += w4 * r2; ve[3] += w4 * r3;
    }
#pragma unroll
    for (int r = 0; r < 4; r++) *(f32x4*)&part[r][wv][c4] = ve[r];
  }
  __syncthreads();
  float bkc = bk[col];
  float e_a = up_a * bkc, e_b = up_b * bkc;
#pragma unroll
  for (int w = 0; w < 8; w++) { e_a += part[row_a][w][col]; e_b += part[row_b][w][col]; }
  e_a *= 0.0078125f;
  e_b *= 0.0078125f;
  // softmax over 256 p per row
  float m_a = e_a, m_b = e_b;
#pragma unroll
  for (int d = 32; d > 0; d >>= 1) {
    m_a = fmaxf(m_a, __shfl_xor(m_a, d, 64));
    m_b = fmaxf(m_b, __shfl_xor(m_b, d, 64));
  }
  if (ln == 0) { redB[row_a][wv & 3] = m_a; redB[row_b][wv & 3] = m_b; }
  __syncthreads();
  m_a = fmaxf(fmaxf(redB[row_a][0], redB[row_a][1]), fmaxf(redB[row_a][2], redB[row_a][3]));
  m_b = fmaxf(fmaxf(redB[row_b][0], redB[row_b][1]), fmaxf(redB[row_b][2], redB[row_b][3]));
  e_a = __expf(e_a - m_a);
  e_b = __expf(e_b - m_b);
  float s_a = e_a, s_b = e_b;
#pragma unroll
  for (int d = 32; d > 0; d >>= 1) {
    s_a += __shfl_xor(s_a, d, 64);
    s_b += __shfl_xor(s_b, d, 64);
  }
  if (ln == 0) { redC[row_a][wv & 3] = s_a; redC[row_b][wv & 3] = s_b; }
  __syncthreads();
  float inv_a = 1.f / (redC[row_a][0] + redC[row_a][1] + redC[row_a][2] + redC[row_a][3]);
  float inv_b = 1.f / (redC[row_b][0] + redC[row_b][1] + redC[row_b][2] + redC[row_b][3]);
  float at_a = e_a * inv_a, at_b = e_b * inv_b;
  attS[row_a][col] = at_a;
  attS[row_b][col] = at_b;
  // bo partials
  float bvc = bv[col];
  float ba = at_a * bvc, bb = at_b * bvc;
#pragma unroll
  for (int d = 32; d > 0; d >>= 1) {
    ba += __shfl_xor(ba, d, 64);
    bb += __shfl_xor(bb, d, 64);
  }
  if (ln == 0) { redD[row_a][wv & 3] = ba; redD[row_b][wv & 3] = bb; }
  __syncthreads();  // also publishes attS for the Mv loop
  if (t < 4) bo[b * CC + o0 + t] = redD[t][0] + redD[t][1] + redD[t][2] + redD[t][3];
  // ---- Mv partials: wave covers d-range; lane covers 4 c' via Wv float4 rows
  {
    f32x4 vm[4] = {};
    const float* wp = Wv + (size_t)d0 * CC + c4;
#pragma unroll 8
    for (int i = 0; i < 32; i++) {
      f32x4 w4 = *(const f32x4*)(wp + (size_t)i * CC);
      float a0 = attS[0][d0 + i], a1 = attS[1][d0 + i];
      float a2 = attS[2][d0 + i], a3 = attS[3][d0 + i];
      vm[0] += w4 * a0; vm[1] += w4 * a1; vm[2] += w4 * a2; vm[3] += w4 * a3;
    }
#pragma unroll
    for (int r = 0; r < 4; r++) *(f32x4*)&part[r][wv][c4] = vm[r];
  }
  __syncthreads();
  float mv_a = 0.f, mv_b = 0.f;
#pragma unroll
  for (int w = 0; w < 8; w++) { mv_a += part[row_a][w][col]; mv_b += part[row_b][w][col]; }
  Mvb[((size_t)b * CC + o0 + row_a) * CC + col] = f2bf(mv_a);
  Mvb[((size_t)b * CC + o0 + row_b) * CC + col] = f2bf(mv_b);
}

// out v5: 256(c) x 128(n) tile, 8 waves 4(c)x2(n), 2 blocks/CU, T3-min
// 2-phase pipeline: dbuf 24 KB panels (A 256x32 + B 128x32), next-step STAGE
// issued before current MFMA, one barrier per BK=32 step. K-order unchanged.
// float4 LDS-restage epilogue kept (union, post-barrier).
__global__ __launch_bounds__(512, 4) void out_kernel(const u16* __restrict__ Mvb,
                                                     const u16* __restrict__ xbT,
                                                     const float* __restrict__ bo,
                                                     const float* __restrict__ x,
                                                     float* __restrict__ out) {
  __shared__ union {
    struct { u16 As[2][256 * 32]; u16 Bs[2][128 * 32]; } st;  // 48 KB
    float scr[8][64][20];                                     // 40 KB
  } sm;
  int tid = threadIdx.x;
  int n0 = blockIdx.x * 128, bz = blockIdx.y;
  const u16* A = Mvb + (size_t)bz * CC * CC;
  const u16* Bt = xbT + ((size_t)bz * NN + n0) * CC;
  f32x4 acc[4][4] = {};
  int wave = tid >> 6, lane = tid & 63;
  int mb = (wave & 3) * 64, nb = (wave >> 2) * 64;
  int quad = lane >> 4, l16 = lane & 15, q8 = quad * 8;
  stage256x32_w8(A, CC, sm.st.As[0], tid);
  stage128x32_w8(Bt, CC, sm.st.Bs[0], tid);
  __syncthreads();
  for (int t = 0; t < 8; t++) {
    if (t < 7) {
      stage256x32_w8(A + (t + 1) * 32, CC, sm.st.As[(t + 1) & 1], tid);
      stage128x32_w8(Bt + (t + 1) * 32, CC, sm.st.Bs[(t + 1) & 1], tid);
    }
    mfma_tile(sm.st.As[t & 1], sm.st.Bs[t & 1], mb, nb, l16, q8, acc);
    __syncthreads();
  }
  // epilogue: wave-local acc transpose through LDS, then float4 streaming
  int l4 = lane >> 2;   // row within 16
  int cgl = lane & 3;   // colgroup (4 floats)
  float bc[4];
#pragma unroll
  for (int kq = 0; kq < 4; kq++) bc[kq] = bo[bz * CC + mb + kq * 16 + l4];
#pragma unroll
  for (int j = 0; j < 4; j++) {
#pragma unroll
    for (int i = 0; i < 4; i++)
#pragma unroll
      for (int r = 0; r < 4; r++)
        sm.scr[wave][i * 16 + quad * 4 + r][l16] = acc[i][j][r];
    // wave-private scratch; in-order LDS + compiler waitcnts give consistency
#pragma unroll
    for (int kq = 0; kq < 4; kq++) {
      int rloc = kq * 16 + l4;
      f32x4 v4 = *(const f32x4*)&sm.scr[wave][rloc][cgl * 4];
      int cg = mb + rloc;
      int ng = n0 + nb + j * 16 + cgl * 4;
      size_t idx = ((size_t)bz * CC + cg) * NN + ng;
      float4 xv = *(const float4*)&x[idx];
      float4 o4;
      o4.x = v4[0] + bc[kq] + xv.x;
      o4.y = v4[1] + bc[kq] + xv.y;
      o4.z = v4[2] + bc[kq] + xv.z;
      o4.w = v4[3] + bc[kq] + xv.w;
      *(float4*)&out[idx] = o4;
    }
  }
}

extern "C" void kernel_launch(void* const* d_in, const int* in_sizes, int n_in,
                              void* d_out, int out_size, void* d_ws, size_t ws_size,
                              hipStream_t stream) {
  (void)in_sizes; (void)n_in; (void)out_size; (void)ws_size;
  const float* x = (const float*)d_in[0];
  const float* wq = (const float*)d_in[1];
  const float* bq = (const float*)d_in[2];
  const float* wk = (const float*)d_in[3];
  const float* bk = (const float*)d_in[4];
  const float* wv = (const float*)d_in[5];
  const float* bv = (const float*)d_in[6];
  float* out = (float*)d_out;

  char* ws = (char*)d_ws;
  u16* xb      = (u16*)(ws + 0);            // 32 MiB  (B,C,N) bf16
  u16* xbT     = (u16*)(ws + 33554432);     // 32 MiB  (B,N,C) bf16
  float* Gp    = (float*)(ws + 67108864);   // 32 MiB  (NSL,B,C,C) fp32 partials
  float* G     = (float*)(ws + 100663296);  // 1 MiB
  float* s_prt = (float*)(ws + 101711872);  // 512 KiB (B,NT,C)
  float* s     = (float*)(ws + 102760448);  // 4 KiB
  u16* Mvb     = (u16*)(ws + 102764544);    // 512 KiB
  float* bo    = (float*)(ws + 103288832);  // 4 KiB
  float* WkT   = (float*)(ws + 103292928);  // 256 KiB

  prep_kernel<<<dim3(NN / 128, CC / 64, BB), 256, 0, stream>>>(x, xb, xbT, s_prt);
  gram_kernel<<<dim3(2, NSL, BB), 512, 0, stream>>>(xb, Gp);
  reduce_kernel<<<256, 256, 0, stream>>>(Gp, s_prt, wk, G, s, WkT);
  mid_kernel<<<dim3(CC / 4, BB), 512, 0, stream>>>(G, s, wq, WkT, wv, bq, bk, bv, Mvb, bo);
  out_kernel<<<dim3(NN / 128, BB), 512, 0, stream>>>(Mvb, xbT, bo, x, out);
}